// Round 6
// baseline (931.193 us; speedup 1.0000x reference)
//
#include <hip/hip_runtime.h>
#include <cstdio>

// MoE top-2 FFN: B=4,S=2048,D=1024 -> T=8192 tokens; E=8, H=4096, K_TOP=2.
// Round 6: 256x256/BK=64/8-wave grouped GEMM, 2-phase pipeline with inline-asm
// ds_read_b128 (dodges waitcnt-legalizer LDS-DMA aliasing drains), manual
// lgkmcnt(0)+sched_barrier(0) per rule #18, vmcnt(0)+s_barrier once per K-tile.
// Prep work (W transposes + router + fill) fused into one role-partitioned kernel.

#define T_TOK 8192
#define DIM   1024
#define NEXP  8
#define HID   4096
#define MAXR  18432  // 16384 rows + 8 experts * up-to-255 pad, rounded to 256

typedef float          f32x4   __attribute__((ext_vector_type(4)));
typedef short          bf16x8  __attribute__((ext_vector_type(8)));
typedef unsigned short u16x4   __attribute__((ext_vector_type(4)));

static __device__ __forceinline__ unsigned short f2bf(float f) {
  unsigned int u = __builtin_bit_cast(unsigned int, f);
  u = (u + 0x7FFFu + ((u >> 16) & 1u)) >> 16;   // round-nearest-even (finite inputs)
  return (unsigned short)u;
}

// async global->LDS, 16B per lane; LDS dest = wave-uniform base + lane*16
static __device__ __forceinline__ void gl16(const void* g, void* l) {
  __builtin_amdgcn_global_load_lds(
      (const __attribute__((address_space(1))) unsigned int*)g,
      (__attribute__((address_space(3))) unsigned int*)l,
      16, 0, 0);
}

// inline-asm LDS read: opaque to the waitcnt legalizer (no auto vmcnt(0)).
// Caller MUST lgkmcnt(0)+sched_barrier(0) before consuming the result.
template <int OFF>
static __device__ __forceinline__ bf16x8 dsr128(unsigned addr) {
  bf16x8 r;
  asm volatile("ds_read_b128 %0, %1 offset:%2" : "=v"(r) : "v"(addr), "i"(OFF));
  return r;
}

// ---------------- device bodies for the fused prep kernel --------------------
static __device__ __forceinline__ void transpose_body(const float* __restrict__ W,
                                                      unsigned short* __restrict__ WT,
                                                      int R, int C, int bx, int by, int e,
                                                      float (*tile)[33]) {
  int c0 = bx * 32, r0 = by * 32;
  const float* Wp = W + (size_t)e * R * C;
  unsigned short* Op = WT + (size_t)e * R * C;
  int tr = threadIdx.x >> 3;
  int tc = (threadIdx.x & 7) * 4;
  float4 v = *(const float4*)(Wp + (size_t)(r0 + tr) * C + c0 + tc);
  tile[tr][tc] = v.x; tile[tr][tc + 1] = v.y; tile[tr][tc + 2] = v.z; tile[tr][tc + 3] = v.w;
  __syncthreads();
  int oc  = threadIdx.x >> 3;
  int orr = (threadIdx.x & 7) * 4;
  u16x4 o;
#pragma unroll
  for (int j = 0; j < 4; ++j) o[j] = f2bf(tile[orr + j][oc]);
  *(u16x4*)(Op + (size_t)(c0 + oc) * R + r0 + orr) = o;
}

static __device__ __forceinline__ void router_body(int blk, const float* __restrict__ x,
                                                   const float* __restrict__ Wr,
                                                   const float* __restrict__ br,
                                                   int* __restrict__ meta,
                                                   int2* __restrict__ top_i,
                                                   float2* __restrict__ top_w) {
  int lane = threadIdx.x & 63;
  int wid  = threadIdx.x >> 6;
  int t = blk * 4 + wid;
  const float* xp = x + (size_t)t * DIM + lane * 16;
  float acc[NEXP];
#pragma unroll
  for (int e = 0; e < NEXP; ++e) acc[e] = 0.f;
#pragma unroll
  for (int j = 0; j < 16; j += 4) {
    float4 xv = *(const float4*)(xp + j);
    const float* wp = Wr + (size_t)(lane * 16 + j) * NEXP;
#pragma unroll
    for (int jj = 0; jj < 4; ++jj) {
      float xs = jj == 0 ? xv.x : jj == 1 ? xv.y : jj == 2 ? xv.z : xv.w;
      float4 w0 = *(const float4*)(wp + jj * NEXP);
      float4 w1 = *(const float4*)(wp + jj * NEXP + 4);
      acc[0] += xs * w0.x; acc[1] += xs * w0.y; acc[2] += xs * w0.z; acc[3] += xs * w0.w;
      acc[4] += xs * w1.x; acc[5] += xs * w1.y; acc[6] += xs * w1.z; acc[7] += xs * w1.w;
    }
  }
#pragma unroll
  for (int off = 32; off > 0; off >>= 1) {
#pragma unroll
    for (int e = 0; e < NEXP; ++e) acc[e] += __shfl_xor(acc[e], off);
  }
  if (lane == 0) {
    float l[NEXP];
#pragma unroll
    for (int e = 0; e < NEXP; ++e) l[e] = acc[e] + br[e];
    int e1 = 0;
#pragma unroll
    for (int e = 1; e < NEXP; ++e) if (l[e] > l[e1]) e1 = e;      // ties -> lower idx
    int e2 = (e1 == 0) ? 1 : 0;
#pragma unroll
    for (int e = 0; e < NEXP; ++e) if (e != e1 && l[e] > l[e2]) e2 = e;
    float g  = expf(l[e2] - l[e1]);              // softmax over top-2 == renorm of full softmax
    float w1 = 1.f / (1.f + g);
    top_i[t] = make_int2(e1, e2);
    top_w[t] = make_float2(w1, 1.f - w1);
    atomicAdd(&meta[e1], 1);
    atomicAdd(&meta[e2], 1);
  }
}

// ---- fused prep: [0,32768) W1 transpose, [32768,65536) W2 transpose,
//      [65536,67584) router, [67584,67656) fill pad-row arrays ---------------
__global__ __launch_bounds__(256) void prep_k(const float* __restrict__ W1,
                                              const float* __restrict__ W2,
                                              unsigned short* __restrict__ W1bT,
                                              unsigned short* __restrict__ W2bT,
                                              const float* __restrict__ x,
                                              const float* __restrict__ Wr,
                                              const float* __restrict__ br,
                                              int* __restrict__ meta,
                                              int2* __restrict__ top_i,
                                              float2* __restrict__ top_w,
                                              int* __restrict__ tok_of_row,
                                              float* __restrict__ wt_of_row) {
  __shared__ float tile[32][33];
  int id = blockIdx.x;
  if (id < 32768) {                              // W1[e][D][H] -> [e][H][D]
    transpose_body(W1, W1bT, DIM, HID, id & 127, (id >> 7) & 31, id >> 12, tile);
  } else if (id < 65536) {                       // W2[e][H][D] -> [e][D][H]
    int id2 = id - 32768;
    transpose_body(W2, W2bT, HID, DIM, id2 & 31, (id2 >> 5) & 127, id2 >> 12, tile);
  } else if (id < 67584) {
    router_body(id - 65536, x, Wr, br, meta, top_i, top_w);
  } else {
    int i = (id - 67584) * 256 + threadIdx.x;
    if (i < MAXR) { tok_of_row[i] = 0; wt_of_row[i] = 0.f; }
  }
}

// -------- prefix: padded (x256) offsets ------------------------------------
__global__ void prefix_k(int* __restrict__ meta) {
  if (threadIdx.x == 0) {
    int s = 0;
#pragma unroll
    for (int e = 0; e < NEXP; ++e) {
      meta[16 + e] = s;                          // poff[e]
      s += (meta[e] + 255) & ~255;
    }
    meta[24] = s;                                // poff[8]
    meta[25] = s;                                // total_padded (<= MAXR always)
  }
}

// ---------------- scatter: token -> packed expert row ------------------------
__global__ __launch_bounds__(256) void scatter_k(const int2* __restrict__ top_i,
                                                 const float2* __restrict__ top_w,
                                                 int* __restrict__ meta,
                                                 int* __restrict__ row_of,
                                                 int* __restrict__ tok_of_row,
                                                 float* __restrict__ wt_of_row) {
  int t = blockIdx.x * 256 + threadIdx.x;
  int2  ei = top_i[t];
  float2 w = top_w[t];
  int p = atomicAdd(&meta[8 + ei.x], 1);
  int r = meta[16 + ei.x] + p;
  tok_of_row[r] = t; wt_of_row[r] = w.x; row_of[t * 2] = r;
  p = atomicAdd(&meta[8 + ei.y], 1);
  r = meta[16 + ei.y] + p;
  tok_of_row[r] = t; wt_of_row[r] = w.y; row_of[t * 2 + 1] = r;
}

// ---------------- gather: xg[r][:] = bf16(x[tok[r]][:]) ----------------------
__global__ __launch_bounds__(256) void gather_k(const float* __restrict__ x,
                                                const int* __restrict__ tok_of_row,
                                                const int* __restrict__ meta,
                                                unsigned short* __restrict__ xg) {
  int r = blockIdx.x;
  if (r >= meta[25]) return;
  int t = tok_of_row[r];
  int c = threadIdx.x * 4;
  float4 v = *(const float4*)(x + (size_t)t * DIM + c);
  u16x4 o;
  o[0] = f2bf(v.x); o[1] = f2bf(v.y); o[2] = f2bf(v.z); o[3] = f2bf(v.w);
  *(u16x4*)(xg + (size_t)r * DIM + c) = o;
}

// ---------------- 2-phase 256x256 grouped GEMM -------------------------------
// LDS 128KB: A buf b at byte b*32768 ([256 rows][8 slots x 16B], row stride 128B,
// slot XOR-swizzled by row&7), B buf b at 65536 + b*32768, same layout.
// Per K-tile: stage next tile (8 gl16) -> 24 asm ds_read_b128 in two k-steps,
// each {12 reads; lgkmcnt(0); sched_barrier; setprio(1); 32 MFMA; setprio(0)}
// -> vmcnt(0) -> s_barrier.  8 waves 2Mx4N, wave owns 128x64 of C.

template <int NB, int KTOT>
static __device__ __forceinline__ void stage_tile(unsigned short* lds,
                                                  const unsigned short* pA,
                                                  const unsigned short* pB,
                                                  int wid, int kt) {
#pragma unroll
  for (int h = 0; h < 2; ++h)
#pragma unroll
    for (int sw = 0; sw < 2; ++sw) {
      int go = (h * 128 + sw * 64) * KTOT + kt * 64;
      int lo = NB * 16384 + h * 8192 + sw * 4096 + wid * 512;    // shorts
      gl16(pA + go, lds + lo);
      gl16(pB + go, lds + 32768 + lo);
    }
}

template <int RB>   // RB = buf*32768 (bytes)
static __device__ __forceinline__ void kstep(unsigned aA, unsigned aB, f32x4 (&acc)[8][4]) {
  bf16x8 a[8], b[4];
  a[0] = dsr128<RB +     0>(aA); a[1] = dsr128<RB +  2048>(aA);
  a[2] = dsr128<RB +  4096>(aA); a[3] = dsr128<RB +  6144>(aA);
  a[4] = dsr128<RB +  8192>(aA); a[5] = dsr128<RB + 10240>(aA);
  a[6] = dsr128<RB + 12288>(aA); a[7] = dsr128<RB + 14336>(aA);
  b[0] = dsr128<RB +     0>(aB); b[1] = dsr128<RB +  2048>(aB);
  b[2] = dsr128<RB +  4096>(aB); b[3] = dsr128<RB +  6144>(aB);
  asm volatile("s_waitcnt lgkmcnt(0)" ::);       // data actually in VGPRs now
  __builtin_amdgcn_sched_barrier(0);             // rule #18: pin MFMAs below the wait
  __builtin_amdgcn_s_setprio(1);
#pragma unroll
  for (int fr = 0; fr < 8; ++fr)
#pragma unroll
    for (int j = 0; j < 4; ++j)
      acc[fr][j] = __builtin_amdgcn_mfma_f32_16x16x32_bf16(a[fr], b[j], acc[fr][j], 0, 0, 0);
  __builtin_amdgcn_s_setprio(0);
}

template <int B, bool STG, int KTOT>
static __device__ __forceinline__ void gtile(unsigned short* lds,
                                             const unsigned short* pA,
                                             const unsigned short* pB,
                                             int wid, int kt_next,
                                             unsigned aA0, unsigned aA1,
                                             unsigned aB0, unsigned aB1,
                                             f32x4 (&acc)[8][4]) {
  if constexpr (STG) stage_tile<B ^ 1, KTOT>(lds, pA, pB, wid, kt_next);
  kstep<B * 32768>(aA0, aB0, acc);               // k-step s=0 (slots 0..3)
  kstep<B * 32768>(aA1, aB1, acc);               // k-step s=1 (slots 4..7)
  if constexpr (STG) {
    asm volatile("s_waitcnt vmcnt(0)" ::);       // next tile's LDS-DMA landed
    __builtin_amdgcn_s_barrier();                // all waves done reading buf B too
  }
}

template <int KTOT, int NTOT, int EPI>
__global__ __launch_bounds__(512, 2) void gemm2p_k(const unsigned short* __restrict__ A,
                                                   const unsigned short* __restrict__ Bt,
                                                   const float* __restrict__ bias,
                                                   const int* __restrict__ meta,
                                                   const float* __restrict__ wt_of_row,
                                                   const int* __restrict__ tok_of_row,
                                                   void* __restrict__ Cout) {
  constexpr int NTILES = NTOT / 256;
  constexpr int NWG = (MAXR / 256) * NTILES;     // 1152 or 288, both % 8 == 0
  constexpr int NT = KTOT / 64;                  // 16 or 64 (even)
  __shared__ __align__(16) unsigned short lds[65536];   // 128 KiB

  int id = ((int)blockIdx.x & 7) * (NWG / 8) + ((int)blockIdx.x >> 3);  // XCD swizzle
  int row0 = (id / NTILES) * 256;                // n-fast within XCD chunk (A-panel reuse)
  int n0   = (id % NTILES) * 256;
  if (row0 >= meta[25]) return;                  // beyond padded total (block-uniform)
  int e = 0;
  while (meta[17 + e] <= row0) ++e;              // tiles never straddle experts
  const unsigned short* Bp = Bt + (size_t)e * NTOT * KTOT;

  int tid = threadIdx.x;
  int lane = tid & 63, wid = tid >> 6;
  int wm = wid >> 2, wn = wid & 3;               // 2x4 waves, each owns 128x64 of C

  // staging source (T2 write-side): thread granule -> row = tid>>3 (+64*sw+128*h),
  // slot' = tid&7; source col-slot = slot' ^ (row&7) = (tid&7) ^ ((tid>>3)&7)
  int colS = ((tid & 7) ^ ((tid >> 3) & 7)) * 8;
  const unsigned short* pA = A  + (size_t)(row0 + (tid >> 3)) * KTOT + colS;
  const unsigned short* pB = Bp + (size_t)(n0   + (tid >> 3)) * KTOT + colS;

  // fragment read addresses (T2 read-side): row&7 == am&7 for every fragment row
  int g = lane >> 4, am = lane & 15;
  unsigned lb = (unsigned)(unsigned long long)
      (__attribute__((address_space(3))) unsigned short*)lds;
  unsigned sc0 = (unsigned)(((0 * 4 + g) ^ (am & 7)) * 16);
  unsigned sc1 = (unsigned)(((1 * 4 + g) ^ (am & 7)) * 16);
  unsigned aA0 = lb + (unsigned)((wm * 128 + am) * 128) + sc0;
  unsigned aA1 = lb + (unsigned)((wm * 128 + am) * 128) + sc1;
  unsigned aB0 = lb + 65536u + (unsigned)((wn * 64 + am) * 128) + sc0;
  unsigned aB1 = lb + 65536u + (unsigned)((wn * 64 + am) * 128) + sc1;

  f32x4 acc[8][4];
#pragma unroll
  for (int r = 0; r < 8; ++r)
#pragma unroll
    for (int n = 0; n < 4; ++n) acc[r][n] = (f32x4){0.f, 0.f, 0.f, 0.f};

  // prologue: stage tile 0 into buf 0
  stage_tile<0, KTOT>(lds, pA, pB, wid, 0);
  asm volatile("s_waitcnt vmcnt(0)" ::);
  __builtin_amdgcn_s_barrier();

  // main: x2 unrolled so buffers are compile-time
  for (int t = 0; t < NT - 2; t += 2) {
    gtile<0, true, KTOT>(lds, pA, pB, wid, t + 1, aA0, aA1, aB0, aB1, acc);
    gtile<1, true, KTOT>(lds, pA, pB, wid, t + 2, aA0, aA1, aB0, aB1, acc);
  }
  gtile<0, true, KTOT>(lds, pA, pB, wid, NT - 1, aA0, aA1, aB0, aB1, acc);
  gtile<1, false, KTOT>(lds, pA, pB, wid, 0, aA0, aA1, aB0, aB1, acc);

  // epilogue.  C/D: col = lane&15, row = (lane>>4)*4 + reg  (validated r2-r5)
  int rb2 = row0 + wm * 128 + ((lane >> 4) << 2);
  int nb2 = n0 + wn * 64 + am;
  if constexpr (EPI == 0) {
    unsigned short* Hp = (unsigned short*)Cout;
    const float* bp = bias + (size_t)e * NTOT;
#pragma unroll
    for (int r = 0; r < 8; ++r)
#pragma unroll
      for (int n = 0; n < 4; ++n) {
        int ncol = nb2 + n * 16;
        float bv = bp[ncol];
#pragma unroll
        for (int gg = 0; gg < 4; ++gg) {
          int m = rb2 + r * 16 + gg;
          float v = acc[r][n][gg] + bv;
          v = 0.5f * v * (1.f + erff(v * 0.70710678118654752f));   // exact gelu
          Hp[(size_t)m * NTOT + ncol] = f2bf(v);
        }
      }
  } else {
    float* Op = (float*)Cout;
    const float* bp = bias + (size_t)e * NTOT;
#pragma unroll
    for (int r = 0; r < 8; ++r)
#pragma unroll
      for (int gg = 0; gg < 4; ++gg) {
        int m = rb2 + r * 16 + gg;
        float wt = wt_of_row[m];
        if (wt != 0.f) {                         // pad rows excluded (wt exactly 0)
          float* orow = Op + (size_t)tok_of_row[m] * DIM;
#pragma unroll
          for (int n = 0; n < 4; ++n) {
            int ncol = nb2 + n * 16;
            atomicAdd(orow + ncol, (acc[r][n][gg] + bp[ncol]) * wt);
          }
        }
      }
  }
}

extern "C" void kernel_launch(void* const* d_in, const int* in_sizes, int n_in,
                              void* d_out, int out_size, void* d_ws, size_t ws_size,
                              hipStream_t stream) {
  const float* x  = (const float*)d_in[0];
  const float* Wr = (const float*)d_in[1];
  const float* br = (const float*)d_in[2];
  const float* W1 = (const float*)d_in[3];
  const float* b1 = (const float*)d_in[4];
  const float* W2 = (const float*)d_in[5];
  const float* b2 = (const float*)d_in[6];
  float* out = (float*)d_out;

  char* base = (char*)d_ws;
  size_t off = 0;
  auto carve = [&](size_t bytes) -> void* {
    void* r = base + off;
    off = (off + bytes + 255) & ~(size_t)255;
    return r;
  };
  int*            meta       = (int*)carve(26 * 4);
  int2*           top_i      = (int2*)carve((size_t)T_TOK * 8);
  float2*         top_w      = (float2*)carve((size_t)T_TOK * 8);
  int*            row_of     = (int*)carve((size_t)T_TOK * 2 * 4);
  int*            tok_of_row = (int*)carve((size_t)MAXR * 4);
  float*          wt_of_row  = (float*)carve((size_t)MAXR * 4);
  unsigned short* xg         = (unsigned short*)carve((size_t)MAXR * DIM * 2);
  unsigned short* W1bT       = (unsigned short*)carve((size_t)NEXP * DIM * HID * 2);
  unsigned short* W2bT       = (unsigned short*)carve((size_t)NEXP * DIM * HID * 2);
  unsigned short* hbuf       = (unsigned short*)carve((size_t)MAXR * HID * 2);
  if (off > ws_size) {
    fprintf(stderr, "kernel_launch: ws_size too small: need %zu have %zu\n", off, ws_size);
    return;
  }

  hipMemsetAsync(meta, 0, 26 * 4, stream);
  hipMemsetAsync(out, 0, (size_t)out_size * 4, stream);   // GEMM2 atomicAdds into out
  hipLaunchKernelGGL(prep_k, dim3(67656), dim3(256), 0, stream,
                     W1, W2, W1bT, W2bT, x, Wr, br, meta, top_i, top_w,
                     tok_of_row, wt_of_row);
  hipLaunchKernelGGL(prefix_k, dim3(1), dim3(64), 0, stream, meta);
  hipLaunchKernelGGL(scatter_k, dim3(T_TOK / 256), dim3(256), 0, stream,
                     top_i, top_w, meta, row_of, tok_of_row, wt_of_row);
  hipLaunchKernelGGL(gather_k, dim3(MAXR), dim3(256), 0, stream, x, tok_of_row, meta, xg);
  hipLaunchKernelGGL((gemm2p_k<DIM, HID, 0>), dim3((MAXR / 256) * (HID / 256)), dim3(512), 0,
                     stream, xg, W1bT, b1, meta, wt_of_row, tok_of_row, (void*)hbuf);
  hipLaunchKernelGGL((gemm2p_k<HID, DIM, 1>), dim3((MAXR / 256) * (DIM / 256)), dim3(512), 0,
                     stream, hbuf, W2bT, b2, meta, wt_of_row, tok_of_row, (void*)out);
}